// Round 4
// baseline (206.977 us; speedup 1.0000x reference)
//
#include <hip/hip_runtime.h>
#include <stdint.h>
#include <stddef.h>

#define Bb 8
#define Cc 128
#define Hh 96
#define Ww 160
#define HW (Hh*Ww)         // 15360
#define Kk 81

typedef __attribute__((ext_vector_type(8))) short short8;
typedef __attribute__((ext_vector_type(4))) float floatx4;
typedef __attribute__((ext_vector_type(4))) unsigned int uintx4;

__device__ __forceinline__ uint32_t bf16rne(float f) {
  uint32_t u = __float_as_uint(f);
  return (u + 0x7FFFu + ((u >> 16) & 1u)) >> 16;
}

#define SBAR() __builtin_amdgcn_sched_barrier(0)

// ---------------------------------------------------------------------------
// R10: R9 flipped the bottleneck -- corr_t3 is now ~34us, transpose is 57.6us
// with VGPR_Count=16: the allocator serialized the 4-float4 load loop
// (load->drain->LDS-write->next), exposing ~4 full memory latencies per
// block. Same fix that worked for corr in R9: named-register load clusters
// + sched_barrier(0) phase fences, and __launch_bounds__(256,8) to pin
// 32 waves/CU (VGPR cap 64 >= the ~40 needed). Identical data movement and
// rounding -> bit-identical outputs. corr_t3 + fallback unchanged.
// Roofline for transpose: 189MB @ 6.3TB/s ~= 30us (from 57.6).
// ---------------------------------------------------------------------------

// ---- transpose+convert: (B,C,H,W) f32 -> (B,HW,C) bf16 --------------------
#define TPX 32
__global__ __launch_bounds__(256, 8)
void transpose_kernel(const float* __restrict__ x1, const float* __restrict__ x2,
                      ushort* __restrict__ x1t, ushort* __restrict__ x2t) {
  __shared__ float lds[TPX * 130];
  const int t   = threadIdx.x;
  const int b   = blockIdx.y;
  const int hw0 = blockIdx.x * TPX;
  const float* src = blockIdx.z ? x2 : x1;
  ushort*      dst = blockIdx.z ? x2t : x1t;

  // ---- phase 1a: issue ALL 4 global float4 loads (named regs) ----
  const int p4 = t & 7;        // which float4 (4 px) within the 32-px tile
  const int cb = t >> 3;       // 0..31
  const float* sbase = src + (size_t)(b * Cc + cb) * HW + hw0 + p4 * 4;
  floatx4 v0 = *(const floatx4*)(sbase + (size_t) 0 * HW);
  floatx4 v1 = *(const floatx4*)(sbase + (size_t)32 * HW);
  floatx4 v2 = *(const floatx4*)(sbase + (size_t)64 * HW);
  floatx4 v3 = *(const floatx4*)(sbase + (size_t)96 * HW);
  SBAR();

  // ---- phase 1b: scatter to lds[px][c] (stride 130: 2-way max = free) ----
#pragma unroll
  for (int jj = 0; jj < 4; ++jj) lds[(p4 * 4 + jj) * 130 + cb +  0] = v0[jj];
#pragma unroll
  for (int jj = 0; jj < 4; ++jj) lds[(p4 * 4 + jj) * 130 + cb + 32] = v1[jj];
#pragma unroll
  for (int jj = 0; jj < 4; ++jj) lds[(p4 * 4 + jj) * 130 + cb + 64] = v2[jj];
#pragma unroll
  for (int jj = 0; jj < 4; ++jj) lds[(p4 * 4 + jj) * 130 + cb + 96] = v3[jj];

  __syncthreads();

  // ---- phase 2a: issue ALL 16 LDS reads (two 8-channel chunks) ----
  const int px = t >> 3;       // 0..31
  const int k0 = t & 7;        // chunk indices k0 and k0+8
  const float* rowa = &lds[px * 130 + k0 * 8];
  const float* rowb = &lds[px * 130 + (k0 + 8) * 8];
  float f0 = rowa[0], f1 = rowa[1], f2 = rowa[2], f3 = rowa[3];
  float f4 = rowa[4], f5 = rowa[5], f6 = rowa[6], f7 = rowa[7];
  float g0 = rowb[0], g1 = rowb[1], g2 = rowb[2], g3 = rowb[3];
  float g4 = rowb[4], g5 = rowb[5], g6 = rowb[6], g7 = rowb[7];
  SBAR();

  // ---- phase 2b: pack bf16 and issue both 16B stores ----
  uintx4 qa = (uintx4){bf16rne(f0) | (bf16rne(f1) << 16),
                       bf16rne(f2) | (bf16rne(f3) << 16),
                       bf16rne(f4) | (bf16rne(f5) << 16),
                       bf16rne(f6) | (bf16rne(f7) << 16)};
  uintx4 qb = (uintx4){bf16rne(g0) | (bf16rne(g1) << 16),
                       bf16rne(g2) | (bf16rne(g3) << 16),
                       bf16rne(g4) | (bf16rne(g5) << 16),
                       bf16rne(g6) | (bf16rne(g7) << 16)};
  ushort* dbase = &dst[((size_t)b * HW + hw0 + px) * Cc];
  *(uintx4*)&dbase[k0 * 8]       = qa;
  *(uintx4*)&dbase[(k0 + 8) * 8] = qb;
}

// ---- correlation: pinned register pipeline + coalesced epilogue -----------
__device__ __forceinline__ int clampi(int v, int lo, int hi) {
  return v < lo ? lo : (v > hi ? hi : v);
}

#define LOADRAW(dst, tt, ckc)                                                  \
  dst = *(const short8*)&base2c[rowoff##tt + (ckc) * 32];

#define ZSEL(v, tt)                                                            \
  v = (okw && (unsigned)(gh2b + (tt)) < (unsigned)Hh) ? v                      \
      : (short8){0, 0, 0, 0, 0, 0, 0, 0};

__global__ __launch_bounds__(256, 3)
void corr_t3_kernel(const ushort* __restrict__ x1t, const ushort* __restrict__ x2t,
                    float* __restrict__ out) {
  __shared__ float ldsOut[Kk * 66];   // 21384 B, stride-66 pad (bank spread)

  const int tid  = threadIdx.x;
  const int flat = blockIdx.x;
  const int b  = flat & 7;
  const int j  = flat >> 3;        // 0..239
  const int by = j / 10;           // 0..23
  const int bx = j - by * 10;      // 0..9
  const int w0 = bx * 16;
  const int h0 = by * 4;

  const int lane = tid & 63;
  const int wv   = tid >> 6;       // 0..3
  const int vy = wv & 1, vx = wv >> 1;
  const int n = lane & 15, quad = lane >> 4;
  const int s = n >> 3, pw = n & 7;

  floatx4 acc[10];
#pragma unroll
  for (int t = 0; t < 10; ++t) acc[t] = (floatx4){0.f, 0.f, 0.f, 0.f};

  const int gw2  = w0 - 4 + 8 * vx + n;
  const bool okw = (unsigned)gw2 < (unsigned)Ww;
  const int gw2c = clampi(gw2, 0, Ww - 1);
  const int gh2b = h0 - 4 + 2 * vy;

  const ushort* base2c = x2t + ((long)b * HW + gw2c) * Cc + quad * 8;
  const ushort* base1  = x1t + ((long)b * HW + (long)(h0 + 2 * vy + s) * Ww
                                + (w0 + 8 * vx + pw)) * Cc + quad * 8;

  const long rowoff0 = (long)clampi(gh2b + 0, 0, Hh - 1) * (Ww * Cc);
  const long rowoff1 = (long)clampi(gh2b + 1, 0, Hh - 1) * (Ww * Cc);
  const long rowoff2 = (long)clampi(gh2b + 2, 0, Hh - 1) * (Ww * Cc);
  const long rowoff3 = (long)clampi(gh2b + 3, 0, Hh - 1) * (Ww * Cc);
  const long rowoff4 = (long)clampi(gh2b + 4, 0, Hh - 1) * (Ww * Cc);
  const long rowoff5 = (long)clampi(gh2b + 5, 0, Hh - 1) * (Ww * Cc);
  const long rowoff6 = (long)clampi(gh2b + 6, 0, Hh - 1) * (Ww * Cc);
  const long rowoff7 = (long)clampi(gh2b + 7, 0, Hh - 1) * (Ww * Cc);
  const long rowoff8 = (long)clampi(gh2b + 8, 0, Hh - 1) * (Ww * Cc);
  const long rowoff9 = (long)clampi(gh2b + 9, 0, Hh - 1) * (Ww * Cc);

  const short8 bf0 = *(const short8*)&base1[0 * 32];
  const short8 bf1 = *(const short8*)&base1[1 * 32];
  const short8 bf2 = *(const short8*)&base1[2 * 32];
  const short8 bf3 = *(const short8*)&base1[3 * 32];

  short8 aA0, aA1, aA2, aA3, aA4, aA5, aA6, aA7, aA8, aA9;
  short8 aB0, aB1, aB2, aB3, aB4, aB5, aB6, aB7, aB8, aB9;

  LOADRAW(aA0, 0, 0); LOADRAW(aA1, 1, 0); LOADRAW(aA2, 2, 0); LOADRAW(aA3, 3, 0);
  LOADRAW(aA4, 4, 0); LOADRAW(aA5, 5, 0); LOADRAW(aA6, 6, 0); LOADRAW(aA7, 7, 0);
  LOADRAW(aA8, 8, 0); LOADRAW(aA9, 9, 0);
  SBAR();
  LOADRAW(aB0, 0, 1); LOADRAW(aB1, 1, 1); LOADRAW(aB2, 2, 1); LOADRAW(aB3, 3, 1);
  LOADRAW(aB4, 4, 1); LOADRAW(aB5, 5, 1); LOADRAW(aB6, 6, 1); LOADRAW(aB7, 7, 1);
  LOADRAW(aB8, 8, 1); LOADRAW(aB9, 9, 1);
  SBAR();
  ZSEL(aA0, 0); ZSEL(aA1, 1); ZSEL(aA2, 2); ZSEL(aA3, 3); ZSEL(aA4, 4);
  ZSEL(aA5, 5); ZSEL(aA6, 6); ZSEL(aA7, 7); ZSEL(aA8, 8); ZSEL(aA9, 9);
  acc[0] = __builtin_amdgcn_mfma_f32_16x16x32_bf16(aA0, bf0, acc[0], 0, 0, 0);
  acc[1] = __builtin_amdgcn_mfma_f32_16x16x32_bf16(aA1, bf0, acc[1], 0, 0, 0);
  acc[2] = __builtin_amdgcn_mfma_f32_16x16x32_bf16(aA2, bf0, acc[2], 0, 0, 0);
  acc[3] = __builtin_amdgcn_mfma_f32_16x16x32_bf16(aA3, bf0, acc[3], 0, 0, 0);
  acc[4] = __builtin_amdgcn_mfma_f32_16x16x32_bf16(aA4, bf0, acc[4], 0, 0, 0);
  acc[5] = __builtin_amdgcn_mfma_f32_16x16x32_bf16(aA5, bf0, acc[5], 0, 0, 0);
  acc[6] = __builtin_amdgcn_mfma_f32_16x16x32_bf16(aA6, bf0, acc[6], 0, 0, 0);
  acc[7] = __builtin_amdgcn_mfma_f32_16x16x32_bf16(aA7, bf0, acc[7], 0, 0, 0);
  acc[8] = __builtin_amdgcn_mfma_f32_16x16x32_bf16(aA8, bf0, acc[8], 0, 0, 0);
  acc[9] = __builtin_amdgcn_mfma_f32_16x16x32_bf16(aA9, bf0, acc[9], 0, 0, 0);
  SBAR();
  LOADRAW(aA0, 0, 2); LOADRAW(aA1, 1, 2); LOADRAW(aA2, 2, 2); LOADRAW(aA3, 3, 2);
  LOADRAW(aA4, 4, 2); LOADRAW(aA5, 5, 2); LOADRAW(aA6, 6, 2); LOADRAW(aA7, 7, 2);
  LOADRAW(aA8, 8, 2); LOADRAW(aA9, 9, 2);
  SBAR();
  ZSEL(aB0, 0); ZSEL(aB1, 1); ZSEL(aB2, 2); ZSEL(aB3, 3); ZSEL(aB4, 4);
  ZSEL(aB5, 5); ZSEL(aB6, 6); ZSEL(aB7, 7); ZSEL(aB8, 8); ZSEL(aB9, 9);
  acc[0] = __builtin_amdgcn_mfma_f32_16x16x32_bf16(aB0, bf1, acc[0], 0, 0, 0);
  acc[1] = __builtin_amdgcn_mfma_f32_16x16x32_bf16(aB1, bf1, acc[1], 0, 0, 0);
  acc[2] = __builtin_amdgcn_mfma_f32_16x16x32_bf16(aB2, bf1, acc[2], 0, 0, 0);
  acc[3] = __builtin_amdgcn_mfma_f32_16x16x32_bf16(aB3, bf1, acc[3], 0, 0, 0);
  acc[4] = __builtin_amdgcn_mfma_f32_16x16x32_bf16(aB4, bf1, acc[4], 0, 0, 0);
  acc[5] = __builtin_amdgcn_mfma_f32_16x16x32_bf16(aB5, bf1, acc[5], 0, 0, 0);
  acc[6] = __builtin_amdgcn_mfma_f32_16x16x32_bf16(aB6, bf1, acc[6], 0, 0, 0);
  acc[7] = __builtin_amdgcn_mfma_f32_16x16x32_bf16(aB7, bf1, acc[7], 0, 0, 0);
  acc[8] = __builtin_amdgcn_mfma_f32_16x16x32_bf16(aB8, bf1, acc[8], 0, 0, 0);
  acc[9] = __builtin_amdgcn_mfma_f32_16x16x32_bf16(aB9, bf1, acc[9], 0, 0, 0);
  SBAR();
  LOADRAW(aB0, 0, 3); LOADRAW(aB1, 1, 3); LOADRAW(aB2, 2, 3); LOADRAW(aB3, 3, 3);
  LOADRAW(aB4, 4, 3); LOADRAW(aB5, 5, 3); LOADRAW(aB6, 6, 3); LOADRAW(aB7, 7, 3);
  LOADRAW(aB8, 8, 3); LOADRAW(aB9, 9, 3);
  SBAR();
  ZSEL(aA0, 0); ZSEL(aA1, 1); ZSEL(aA2, 2); ZSEL(aA3, 3); ZSEL(aA4, 4);
  ZSEL(aA5, 5); ZSEL(aA6, 6); ZSEL(aA7, 7); ZSEL(aA8, 8); ZSEL(aA9, 9);
  acc[0] = __builtin_amdgcn_mfma_f32_16x16x32_bf16(aA0, bf2, acc[0], 0, 0, 0);
  acc[1] = __builtin_amdgcn_mfma_f32_16x16x32_bf16(aA1, bf2, acc[1], 0, 0, 0);
  acc[2] = __builtin_amdgcn_mfma_f32_16x16x32_bf16(aA2, bf2, acc[2], 0, 0, 0);
  acc[3] = __builtin_amdgcn_mfma_f32_16x16x32_bf16(aA3, bf2, acc[3], 0, 0, 0);
  acc[4] = __builtin_amdgcn_mfma_f32_16x16x32_bf16(aA4, bf2, acc[4], 0, 0, 0);
  acc[5] = __builtin_amdgcn_mfma_f32_16x16x32_bf16(aA5, bf2, acc[5], 0, 0, 0);
  acc[6] = __builtin_amdgcn_mfma_f32_16x16x32_bf16(aA6, bf2, acc[6], 0, 0, 0);
  acc[7] = __builtin_amdgcn_mfma_f32_16x16x32_bf16(aA7, bf2, acc[7], 0, 0, 0);
  acc[8] = __builtin_amdgcn_mfma_f32_16x16x32_bf16(aA8, bf2, acc[8], 0, 0, 0);
  acc[9] = __builtin_amdgcn_mfma_f32_16x16x32_bf16(aA9, bf2, acc[9], 0, 0, 0);
  SBAR();
  ZSEL(aB0, 0); ZSEL(aB1, 1); ZSEL(aB2, 2); ZSEL(aB3, 3); ZSEL(aB4, 4);
  ZSEL(aB5, 5); ZSEL(aB6, 6); ZSEL(aB7, 7); ZSEL(aB8, 8); ZSEL(aB9, 9);
  acc[0] = __builtin_amdgcn_mfma_f32_16x16x32_bf16(aB0, bf3, acc[0], 0, 0, 0);
  acc[1] = __builtin_amdgcn_mfma_f32_16x16x32_bf16(aB1, bf3, acc[1], 0, 0, 0);
  acc[2] = __builtin_amdgcn_mfma_f32_16x16x32_bf16(aB2, bf3, acc[2], 0, 0, 0);
  acc[3] = __builtin_amdgcn_mfma_f32_16x16x32_bf16(aB3, bf3, acc[3], 0, 0, 0);
  acc[4] = __builtin_amdgcn_mfma_f32_16x16x32_bf16(aB4, bf3, acc[4], 0, 0, 0);
  acc[5] = __builtin_amdgcn_mfma_f32_16x16x32_bf16(aB5, bf3, acc[5], 0, 0, 0);
  acc[6] = __builtin_amdgcn_mfma_f32_16x16x32_bf16(aB6, bf3, acc[6], 0, 0, 0);
  acc[7] = __builtin_amdgcn_mfma_f32_16x16x32_bf16(aB7, bf3, acc[7], 0, 0, 0);
  acc[8] = __builtin_amdgcn_mfma_f32_16x16x32_bf16(aB8, bf3, acc[8], 0, 0, 0);
  acc[9] = __builtin_amdgcn_mfma_f32_16x16x32_bf16(aB9, bf3, acc[9], 0, 0, 0);

  // ---- epilogue: scatter to padded LDS, then coalesced full-line writes ----
  const float scale = 1.0f / 128.0f;
  const int prow = 2 * vy + s;           // 0..3 within tile
  const int pcol = 8 * vx + pw;          // 0..15 within tile
#pragma unroll
  for (int t = 0; t < 10; ++t) {
    int di = t - 4 - s;
    if ((unsigned)(di + 4) > 8u) continue;
#pragma unroll
    for (int r = 0; r < 4; ++r) {
      int dj = quad * 4 + r - 4 - pw;
      if ((unsigned)(dj + 4) > 8u) continue;
      int kk = (di + 4) * 9 + (dj + 4);
      ldsOut[kk * 66 + prow * 16 + pcol] = acc[t][r] * scale;
    }
  }
  __syncthreads();

  for (int idx = tid; idx < Kk * 64; idx += 256) {
    int kk  = idx >> 6;
    int rem = idx & 63;                  // hh*16 + ww
    int hh  = rem >> 4;
    int ww  = rem & 15;
    out[((size_t)b * Kk + kk) * HW + (size_t)(h0 + hh) * Ww + (w0 + ww)] =
        ldsOut[kk * 66 + rem];
  }
}

// ---------------------------------------------------------------------------
// R6 kernel kept verbatim as fallback when workspace is too small.
// ---------------------------------------------------------------------------
__global__ __launch_bounds__(512, 4)
void corr_kernel(const float* __restrict__ x1, const float* __restrict__ x2,
                 float* __restrict__ out) {
  __shared__ __align__(16) ushort ldsX2[16*24*40];
  __shared__ __align__(16) ushort ldsX1[8*16*40];

  const int tid = threadIdx.x;
  const int flat = blockIdx.x;
  const int b  = flat & 7;
  const int j  = flat >> 3;
  const int by = j / 10;
  const int bx = j - by * 10;
  const int w0 = bx * 16;
  const int h0 = by * 8;

  const int lane = tid & 63;
  const int wv   = tid >> 6;
  const int vy = wv & 3, vx = wv >> 2;
  const int n = lane & 15, quad = lane >> 4;
  const int s = n >> 3, pw = n & 7;

  floatx4 acc[10];
#pragma unroll
  for (int t = 0; t < 10; ++t) acc[t] = (floatx4){0.f, 0.f, 0.f, 0.f};

  for (int ck = 0; ck < 4; ++ck) {
    const int c0 = ck * 32;
    if (ck) __syncthreads();

#pragma unroll
    for (int it = 0; it < 3; ++it) {
      int T   = it * 512 + tid;
      int w24 = T % 24;
      int t2  = T / 24;
      int rw  = t2 & 15;
      int cg  = t2 >> 4;
      int gh = h0 - 4 + rw;
      int gw = w0 - 4 + w24;
      bool ok = ((unsigned)gh < Hh) && ((unsigned)gw < Ww);
      const float* src = x2 + ((size_t)(b*Cc + c0 + cg*8) * HW + gh*Ww + gw);
      uint32_t p0, p1, p2, p3;
      {
        float a0 = ok ? src[0*HW] : 0.f;
        float a1 = ok ? src[1*HW] : 0.f;
        float a2 = ok ? src[2*HW] : 0.f;
        float a3 = ok ? src[3*HW] : 0.f;
        float a4 = ok ? src[4*HW] : 0.f;
        float a5 = ok ? src[5*HW] : 0.f;
        float a6 = ok ? src[6*HW] : 0.f;
        float a7 = ok ? src[7*HW] : 0.f;
        p0 = bf16rne(a0) | (bf16rne(a1) << 16);
        p1 = bf16rne(a2) | (bf16rne(a3) << 16);
        p2 = bf16rne(a4) | (bf16rne(a5) << 16);
        p3 = bf16rne(a6) | (bf16rne(a7) << 16);
      }
      *(uintx4*)&ldsX2[(rw*24 + w24)*40 + cg*8] = (uintx4){p0, p1, p2, p3};
    }

    {
      int T  = tid;
      int wl = T & 15;
      int t2 = T >> 4;
      int rl = t2 & 7;
      int cg = t2 >> 3;
      const float* src = x1 + ((size_t)(b*Cc + c0 + cg*8) * HW
                               + (h0 + rl)*Ww + (w0 + wl));
      uint32_t p0, p1, p2, p3;
      float a0 = src[0*HW], a1 = src[1*HW], a2 = src[2*HW], a3 = src[3*HW];
      float a4 = src[4*HW], a5 = src[5*HW], a6 = src[6*HW], a7 = src[7*HW];
      p0 = bf16rne(a0) | (bf16rne(a1) << 16);
      p1 = bf16rne(a2) | (bf16rne(a3) << 16);
      p2 = bf16rne(a4) | (bf16rne(a5) << 16);
      p3 = bf16rne(a6) | (bf16rne(a7) << 16);
      *(uintx4*)&ldsX1[(rl*16 + wl)*40 + cg*8] = (uintx4){p0, p1, p2, p3};
    }

    __syncthreads();

    short8 bfrag = *(const short8*)&ldsX1[((2*vy + s)*16 + 8*vx + pw)*40 + quad*8];
#pragma unroll
    for (int t = 0; t < 10; ++t) {
      short8 afrag = *(const short8*)&ldsX2[((2*vy + t)*24 + 8*vx + n)*40 + quad*8];
      acc[t] = __builtin_amdgcn_mfma_f32_16x16x32_bf16(afrag, bfrag, acc[t], 0, 0, 0);
    }
  }

  const float scale = 1.0f / 128.0f;
  const int ph  = h0 + 2*vy + s;
  const int pwg = w0 + 8*vx + pw;
#pragma unroll
  for (int t = 0; t < 10; ++t) {
    int di = t - 4 - s;
    if ((unsigned)(di + 4) > 8u) continue;
#pragma unroll
    for (int r = 0; r < 4; ++r) {
      int dj = quad*4 + r - 4 - pw;
      if ((unsigned)(dj + 4) > 8u) continue;
      int kk = (di + 4) * 9 + (dj + 4);
      out[((size_t)b*Kk + kk) * HW + ph*Ww + pwg] = acc[t][r] * scale;
    }
  }
}

extern "C" void kernel_launch(void* const* d_in, const int* in_sizes, int n_in,
                              void* d_out, int out_size, void* d_ws, size_t ws_size,
                              hipStream_t stream) {
  const float* x1 = (const float*)d_in[0];
  const float* x2 = (const float*)d_in[1];
  float* out = (float*)d_out;

  const size_t elems = (size_t)Bb * HW * Cc;              // 15,728,640
  const size_t need  = 2 * elems * sizeof(ushort);        // 62,914,560 B

  if (d_ws != nullptr && ws_size >= need) {
    ushort* x1t = (ushort*)d_ws;
    ushort* x2t = x1t + elems;
    transpose_kernel<<<dim3(HW / TPX, Bb, 2), dim3(256, 1, 1), 0, stream>>>(
        x1, x2, x1t, x2t);
    corr_t3_kernel<<<dim3(1920, 1, 1), dim3(256, 1, 1), 0, stream>>>(x1t, x2t, out);
  } else {
    corr_kernel<<<dim3(960, 1, 1), dim3(512, 1, 1), 0, stream>>>(x1, x2, out);
  }
}

// Round 5
// 205.936 us; speedup vs baseline: 1.0051x; 1.0051x over previous
//
#include <hip/hip_runtime.h>
#include <stdint.h>
#include <stddef.h>

#define Bb 8
#define Cc 128
#define Hh 96
#define Ww 160
#define HW (Hh*Ww)         // 15360
#define Kk 81

typedef __attribute__((ext_vector_type(8))) short short8;
typedef __attribute__((ext_vector_type(4))) float floatx4;
typedef __attribute__((ext_vector_type(4))) unsigned int uintx4;

__device__ __forceinline__ uint32_t bf16rne(float f) {
  uint32_t u = __float_as_uint(f);
  return (u + 0x7FFFu + ((u >> 16) & 1u)) >> 16;
}

#define SBAR() __builtin_amdgcn_sched_barrier(0)

// ---------------------------------------------------------------------------
// R11: R10's within-tile SBAR clustering was a no-op (58us unchanged) --
// the transpose block is structurally serial: load->scatter->barrier->
// read->store with nothing to hide the load latency behind. Fix: 4-tile
// pipeline per block with double-buffered LDS. Loads for tile i+1 are
// issued BEFORE tile i's {barrier, LDS-read, pack, store} back half
// (~600-900cy of work), so the memory latency is paid concurrently.
// Identical data movement + rounding -> bit-identical outputs.
// corr_t3 (now ~34us) and fallback unchanged.
// ---------------------------------------------------------------------------

// ---- transpose+convert: (B,C,H,W) f32 -> (B,HW,C) bf16, pipelined ---------
#define TPX 32
__global__ __launch_bounds__(256, 4)
void transpose_kernel(const float* __restrict__ x1, const float* __restrict__ x2,
                      ushort* __restrict__ x1t, ushort* __restrict__ x2t) {
  __shared__ float lds[2][TPX * 130];   // 2 x 16640 B
  const int t   = threadIdx.x;
  const int b   = blockIdx.y;
  const float* src = blockIdx.z ? x2 : x1;
  ushort*      dst = blockIdx.z ? x2t : x1t;
  const int tile0 = blockIdx.x * 4;     // each block handles tiles tile0..tile0+3

  const int p4 = t & 7;        // which float4 (4 px) within a 32-px tile
  const int cb = t >> 3;       // 0..31 (channel within group)
  const int px = t >> 3;       // 0..31 (pixel, phase 2)
  const int k0 = t & 7;        // 16B chunk index (phase 2)

  const float* chan = src + (size_t)(b * Cc + cb) * HW + p4 * 4;

  floatx4 v0, v1, v2, v3;

#define TLOAD(ti)                                                              \
  {                                                                            \
    const float* sb = chan + (size_t)(tile0 + (ti)) * TPX;                     \
    v0 = *(const floatx4*)(sb + (size_t) 0 * HW);                              \
    v1 = *(const floatx4*)(sb + (size_t)32 * HW);                              \
    v2 = *(const floatx4*)(sb + (size_t)64 * HW);                              \
    v3 = *(const floatx4*)(sb + (size_t)96 * HW);                              \
  }

#define TSCATTER(B)                                                            \
  {                                                                            \
    float* L = lds[B];                                                         \
    _Pragma("unroll") for (int jj = 0; jj < 4; ++jj)                           \
        L[(p4 * 4 + jj) * 130 + cb +  0] = v0[jj];                             \
    _Pragma("unroll") for (int jj = 0; jj < 4; ++jj)                           \
        L[(p4 * 4 + jj) * 130 + cb + 32] = v1[jj];                             \
    _Pragma("unroll") for (int jj = 0; jj < 4; ++jj)                           \
        L[(p4 * 4 + jj) * 130 + cb + 64] = v2[jj];                             \
    _Pragma("unroll") for (int jj = 0; jj < 4; ++jj)                           \
        L[(p4 * 4 + jj) * 130 + cb + 96] = v3[jj];                             \
  }

#define TDRAIN(ti, B)                                                          \
  {                                                                            \
    const float* rowa = &lds[B][px * 130 + k0 * 8];                            \
    const float* rowb = &lds[B][px * 130 + (k0 + 8) * 8];                      \
    float f0 = rowa[0], f1 = rowa[1], f2 = rowa[2], f3 = rowa[3];              \
    float f4 = rowa[4], f5 = rowa[5], f6 = rowa[6], f7 = rowa[7];              \
    float g0 = rowb[0], g1 = rowb[1], g2 = rowb[2], g3 = rowb[3];              \
    float g4 = rowb[4], g5 = rowb[5], g6 = rowb[6], g7 = rowb[7];              \
    uintx4 qa = (uintx4){bf16rne(f0) | (bf16rne(f1) << 16),                    \
                         bf16rne(f2) | (bf16rne(f3) << 16),                    \
                         bf16rne(f4) | (bf16rne(f5) << 16),                    \
                         bf16rne(f6) | (bf16rne(f7) << 16)};                   \
    uintx4 qb = (uintx4){bf16rne(g0) | (bf16rne(g1) << 16),                    \
                         bf16rne(g2) | (bf16rne(g3) << 16),                    \
                         bf16rne(g4) | (bf16rne(g5) << 16),                    \
                         bf16rne(g6) | (bf16rne(g7) << 16)};                   \
    ushort* dbase =                                                            \
        &dst[((size_t)b * HW + (size_t)(tile0 + (ti)) * TPX + px) * Cc];       \
    *(uintx4*)&dbase[k0 * 8]       = qa;                                       \
    *(uintx4*)&dbase[(k0 + 8) * 8] = qb;                                       \
  }

  TLOAD(0);
  // tile 0 (buf 0), prefetch tile 1
  TSCATTER(0); SBAR(); TLOAD(1); SBAR(); __syncthreads();
  TDRAIN(0, 0); __syncthreads();
  // tile 1 (buf 1), prefetch tile 2
  TSCATTER(1); SBAR(); TLOAD(2); SBAR(); __syncthreads();
  TDRAIN(1, 1); __syncthreads();
  // tile 2 (buf 0), prefetch tile 3
  TSCATTER(0); SBAR(); TLOAD(3); SBAR(); __syncthreads();
  TDRAIN(2, 0); __syncthreads();
  // tile 3 (buf 1)
  TSCATTER(1); __syncthreads();
  TDRAIN(3, 1);

#undef TLOAD
#undef TSCATTER
#undef TDRAIN
}

// ---- correlation: pinned register pipeline + coalesced epilogue -----------
__device__ __forceinline__ int clampi(int v, int lo, int hi) {
  return v < lo ? lo : (v > hi ? hi : v);
}

#define LOADRAW(dst, tt, ckc)                                                  \
  dst = *(const short8*)&base2c[rowoff##tt + (ckc) * 32];

#define ZSEL(v, tt)                                                            \
  v = (okw && (unsigned)(gh2b + (tt)) < (unsigned)Hh) ? v                      \
      : (short8){0, 0, 0, 0, 0, 0, 0, 0};

__global__ __launch_bounds__(256, 3)
void corr_t3_kernel(const ushort* __restrict__ x1t, const ushort* __restrict__ x2t,
                    float* __restrict__ out) {
  __shared__ float ldsOut[Kk * 66];   // 21384 B, stride-66 pad (bank spread)

  const int tid  = threadIdx.x;
  const int flat = blockIdx.x;
  const int b  = flat & 7;
  const int j  = flat >> 3;        // 0..239
  const int by = j / 10;           // 0..23
  const int bx = j - by * 10;      // 0..9
  const int w0 = bx * 16;
  const int h0 = by * 4;

  const int lane = tid & 63;
  const int wv   = tid >> 6;       // 0..3
  const int vy = wv & 1, vx = wv >> 1;
  const int n = lane & 15, quad = lane >> 4;
  const int s = n >> 3, pw = n & 7;

  floatx4 acc[10];
#pragma unroll
  for (int t = 0; t < 10; ++t) acc[t] = (floatx4){0.f, 0.f, 0.f, 0.f};

  const int gw2  = w0 - 4 + 8 * vx + n;
  const bool okw = (unsigned)gw2 < (unsigned)Ww;
  const int gw2c = clampi(gw2, 0, Ww - 1);
  const int gh2b = h0 - 4 + 2 * vy;

  const ushort* base2c = x2t + ((long)b * HW + gw2c) * Cc + quad * 8;
  const ushort* base1  = x1t + ((long)b * HW + (long)(h0 + 2 * vy + s) * Ww
                                + (w0 + 8 * vx + pw)) * Cc + quad * 8;

  const long rowoff0 = (long)clampi(gh2b + 0, 0, Hh - 1) * (Ww * Cc);
  const long rowoff1 = (long)clampi(gh2b + 1, 0, Hh - 1) * (Ww * Cc);
  const long rowoff2 = (long)clampi(gh2b + 2, 0, Hh - 1) * (Ww * Cc);
  const long rowoff3 = (long)clampi(gh2b + 3, 0, Hh - 1) * (Ww * Cc);
  const long rowoff4 = (long)clampi(gh2b + 4, 0, Hh - 1) * (Ww * Cc);
  const long rowoff5 = (long)clampi(gh2b + 5, 0, Hh - 1) * (Ww * Cc);
  const long rowoff6 = (long)clampi(gh2b + 6, 0, Hh - 1) * (Ww * Cc);
  const long rowoff7 = (long)clampi(gh2b + 7, 0, Hh - 1) * (Ww * Cc);
  const long rowoff8 = (long)clampi(gh2b + 8, 0, Hh - 1) * (Ww * Cc);
  const long rowoff9 = (long)clampi(gh2b + 9, 0, Hh - 1) * (Ww * Cc);

  const short8 bf0 = *(const short8*)&base1[0 * 32];
  const short8 bf1 = *(const short8*)&base1[1 * 32];
  const short8 bf2 = *(const short8*)&base1[2 * 32];
  const short8 bf3 = *(const short8*)&base1[3 * 32];

  short8 aA0, aA1, aA2, aA3, aA4, aA5, aA6, aA7, aA8, aA9;
  short8 aB0, aB1, aB2, aB3, aB4, aB5, aB6, aB7, aB8, aB9;

  LOADRAW(aA0, 0, 0); LOADRAW(aA1, 1, 0); LOADRAW(aA2, 2, 0); LOADRAW(aA3, 3, 0);
  LOADRAW(aA4, 4, 0); LOADRAW(aA5, 5, 0); LOADRAW(aA6, 6, 0); LOADRAW(aA7, 7, 0);
  LOADRAW(aA8, 8, 0); LOADRAW(aA9, 9, 0);
  SBAR();
  LOADRAW(aB0, 0, 1); LOADRAW(aB1, 1, 1); LOADRAW(aB2, 2, 1); LOADRAW(aB3, 3, 1);
  LOADRAW(aB4, 4, 1); LOADRAW(aB5, 5, 1); LOADRAW(aB6, 6, 1); LOADRAW(aB7, 7, 1);
  LOADRAW(aB8, 8, 1); LOADRAW(aB9, 9, 1);
  SBAR();
  ZSEL(aA0, 0); ZSEL(aA1, 1); ZSEL(aA2, 2); ZSEL(aA3, 3); ZSEL(aA4, 4);
  ZSEL(aA5, 5); ZSEL(aA6, 6); ZSEL(aA7, 7); ZSEL(aA8, 8); ZSEL(aA9, 9);
  acc[0] = __builtin_amdgcn_mfma_f32_16x16x32_bf16(aA0, bf0, acc[0], 0, 0, 0);
  acc[1] = __builtin_amdgcn_mfma_f32_16x16x32_bf16(aA1, bf0, acc[1], 0, 0, 0);
  acc[2] = __builtin_amdgcn_mfma_f32_16x16x32_bf16(aA2, bf0, acc[2], 0, 0, 0);
  acc[3] = __builtin_amdgcn_mfma_f32_16x16x32_bf16(aA3, bf0, acc[3], 0, 0, 0);
  acc[4] = __builtin_amdgcn_mfma_f32_16x16x32_bf16(aA4, bf0, acc[4], 0, 0, 0);
  acc[5] = __builtin_amdgcn_mfma_f32_16x16x32_bf16(aA5, bf0, acc[5], 0, 0, 0);
  acc[6] = __builtin_amdgcn_mfma_f32_16x16x32_bf16(aA6, bf0, acc[6], 0, 0, 0);
  acc[7] = __builtin_amdgcn_mfma_f32_16x16x32_bf16(aA7, bf0, acc[7], 0, 0, 0);
  acc[8] = __builtin_amdgcn_mfma_f32_16x16x32_bf16(aA8, bf0, acc[8], 0, 0, 0);
  acc[9] = __builtin_amdgcn_mfma_f32_16x16x32_bf16(aA9, bf0, acc[9], 0, 0, 0);
  SBAR();
  LOADRAW(aA0, 0, 2); LOADRAW(aA1, 1, 2); LOADRAW(aA2, 2, 2); LOADRAW(aA3, 3, 2);
  LOADRAW(aA4, 4, 2); LOADRAW(aA5, 5, 2); LOADRAW(aA6, 6, 2); LOADRAW(aA7, 7, 2);
  LOADRAW(aA8, 8, 2); LOADRAW(aA9, 9, 2);
  SBAR();
  ZSEL(aB0, 0); ZSEL(aB1, 1); ZSEL(aB2, 2); ZSEL(aB3, 3); ZSEL(aB4, 4);
  ZSEL(aB5, 5); ZSEL(aB6, 6); ZSEL(aB7, 7); ZSEL(aB8, 8); ZSEL(aB9, 9);
  acc[0] = __builtin_amdgcn_mfma_f32_16x16x32_bf16(aB0, bf1, acc[0], 0, 0, 0);
  acc[1] = __builtin_amdgcn_mfma_f32_16x16x32_bf16(aB1, bf1, acc[1], 0, 0, 0);
  acc[2] = __builtin_amdgcn_mfma_f32_16x16x32_bf16(aB2, bf1, acc[2], 0, 0, 0);
  acc[3] = __builtin_amdgcn_mfma_f32_16x16x32_bf16(aB3, bf1, acc[3], 0, 0, 0);
  acc[4] = __builtin_amdgcn_mfma_f32_16x16x32_bf16(aB4, bf1, acc[4], 0, 0, 0);
  acc[5] = __builtin_amdgcn_mfma_f32_16x16x32_bf16(aB5, bf1, acc[5], 0, 0, 0);
  acc[6] = __builtin_amdgcn_mfma_f32_16x16x32_bf16(aB6, bf1, acc[6], 0, 0, 0);
  acc[7] = __builtin_amdgcn_mfma_f32_16x16x32_bf16(aB7, bf1, acc[7], 0, 0, 0);
  acc[8] = __builtin_amdgcn_mfma_f32_16x16x32_bf16(aB8, bf1, acc[8], 0, 0, 0);
  acc[9] = __builtin_amdgcn_mfma_f32_16x16x32_bf16(aB9, bf1, acc[9], 0, 0, 0);
  SBAR();
  LOADRAW(aB0, 0, 3); LOADRAW(aB1, 1, 3); LOADRAW(aB2, 2, 3); LOADRAW(aB3, 3, 3);
  LOADRAW(aB4, 4, 3); LOADRAW(aB5, 5, 3); LOADRAW(aB6, 6, 3); LOADRAW(aB7, 7, 3);
  LOADRAW(aB8, 8, 3); LOADRAW(aB9, 9, 3);
  SBAR();
  ZSEL(aA0, 0); ZSEL(aA1, 1); ZSEL(aA2, 2); ZSEL(aA3, 3); ZSEL(aA4, 4);
  ZSEL(aA5, 5); ZSEL(aA6, 6); ZSEL(aA7, 7); ZSEL(aA8, 8); ZSEL(aA9, 9);
  acc[0] = __builtin_amdgcn_mfma_f32_16x16x32_bf16(aA0, bf2, acc[0], 0, 0, 0);
  acc[1] = __builtin_amdgcn_mfma_f32_16x16x32_bf16(aA1, bf2, acc[1], 0, 0, 0);
  acc[2] = __builtin_amdgcn_mfma_f32_16x16x32_bf16(aA2, bf2, acc[2], 0, 0, 0);
  acc[3] = __builtin_amdgcn_mfma_f32_16x16x32_bf16(aA3, bf2, acc[3], 0, 0, 0);
  acc[4] = __builtin_amdgcn_mfma_f32_16x16x32_bf16(aA4, bf2, acc[4], 0, 0, 0);
  acc[5] = __builtin_amdgcn_mfma_f32_16x16x32_bf16(aA5, bf2, acc[5], 0, 0, 0);
  acc[6] = __builtin_amdgcn_mfma_f32_16x16x32_bf16(aA6, bf2, acc[6], 0, 0, 0);
  acc[7] = __builtin_amdgcn_mfma_f32_16x16x32_bf16(aA7, bf2, acc[7], 0, 0, 0);
  acc[8] = __builtin_amdgcn_mfma_f32_16x16x32_bf16(aA8, bf2, acc[8], 0, 0, 0);
  acc[9] = __builtin_amdgcn_mfma_f32_16x16x32_bf16(aA9, bf2, acc[9], 0, 0, 0);
  SBAR();
  ZSEL(aB0, 0); ZSEL(aB1, 1); ZSEL(aB2, 2); ZSEL(aB3, 3); ZSEL(aB4, 4);
  ZSEL(aB5, 5); ZSEL(aB6, 6); ZSEL(aB7, 7); ZSEL(aB8, 8); ZSEL(aB9, 9);
  acc[0] = __builtin_amdgcn_mfma_f32_16x16x32_bf16(aB0, bf3, acc[0], 0, 0, 0);
  acc[1] = __builtin_amdgcn_mfma_f32_16x16x32_bf16(aB1, bf3, acc[1], 0, 0, 0);
  acc[2] = __builtin_amdgcn_mfma_f32_16x16x32_bf16(aB2, bf3, acc[2], 0, 0, 0);
  acc[3] = __builtin_amdgcn_mfma_f32_16x16x32_bf16(aB3, bf3, acc[3], 0, 0, 0);
  acc[4] = __builtin_amdgcn_mfma_f32_16x16x32_bf16(aB4, bf3, acc[4], 0, 0, 0);
  acc[5] = __builtin_amdgcn_mfma_f32_16x16x32_bf16(aB5, bf3, acc[5], 0, 0, 0);
  acc[6] = __builtin_amdgcn_mfma_f32_16x16x32_bf16(aB6, bf3, acc[6], 0, 0, 0);
  acc[7] = __builtin_amdgcn_mfma_f32_16x16x32_bf16(aB7, bf3, acc[7], 0, 0, 0);
  acc[8] = __builtin_amdgcn_mfma_f32_16x16x32_bf16(aB8, bf3, acc[8], 0, 0, 0);
  acc[9] = __builtin_amdgcn_mfma_f32_16x16x32_bf16(aB9, bf3, acc[9], 0, 0, 0);

  // ---- epilogue: scatter to padded LDS, then coalesced full-line writes ----
  const float scale = 1.0f / 128.0f;
  const int prow = 2 * vy + s;           // 0..3 within tile
  const int pcol = 8 * vx + pw;          // 0..15 within tile
#pragma unroll
  for (int t = 0; t < 10; ++t) {
    int di = t - 4 - s;
    if ((unsigned)(di + 4) > 8u) continue;
#pragma unroll
    for (int r = 0; r < 4; ++r) {
      int dj = quad * 4 + r - 4 - pw;
      if ((unsigned)(dj + 4) > 8u) continue;
      int kk = (di + 4) * 9 + (dj + 4);
      ldsOut[kk * 66 + prow * 16 + pcol] = acc[t][r] * scale;
    }
  }
  __syncthreads();

  for (int idx = tid; idx < Kk * 64; idx += 256) {
    int kk  = idx >> 6;
    int rem = idx & 63;                  // hh*16 + ww
    int hh  = rem >> 4;
    int ww  = rem & 15;
    out[((size_t)b * Kk + kk) * HW + (size_t)(h0 + hh) * Ww + (w0 + ww)] =
        ldsOut[kk * 66 + rem];
  }
}

// ---------------------------------------------------------------------------
// R6 kernel kept verbatim as fallback when workspace is too small.
// ---------------------------------------------------------------------------
__global__ __launch_bounds__(512, 4)
void corr_kernel(const float* __restrict__ x1, const float* __restrict__ x2,
                 float* __restrict__ out) {
  __shared__ __align__(16) ushort ldsX2[16*24*40];
  __shared__ __align__(16) ushort ldsX1[8*16*40];

  const int tid = threadIdx.x;
  const int flat = blockIdx.x;
  const int b  = flat & 7;
  const int j  = flat >> 3;
  const int by = j / 10;
  const int bx = j - by * 10;
  const int w0 = bx * 16;
  const int h0 = by * 8;

  const int lane = tid & 63;
  const int wv   = tid >> 6;
  const int vy = wv & 3, vx = wv >> 2;
  const int n = lane & 15, quad = lane >> 4;
  const int s = n >> 3, pw = n & 7;

  floatx4 acc[10];
#pragma unroll
  for (int t = 0; t < 10; ++t) acc[t] = (floatx4){0.f, 0.f, 0.f, 0.f};

  for (int ck = 0; ck < 4; ++ck) {
    const int c0 = ck * 32;
    if (ck) __syncthreads();

#pragma unroll
    for (int it = 0; it < 3; ++it) {
      int T   = it * 512 + tid;
      int w24 = T % 24;
      int t2  = T / 24;
      int rw  = t2 & 15;
      int cg  = t2 >> 4;
      int gh = h0 - 4 + rw;
      int gw = w0 - 4 + w24;
      bool ok = ((unsigned)gh < Hh) && ((unsigned)gw < Ww);
      const float* src = x2 + ((size_t)(b*Cc + c0 + cg*8) * HW + gh*Ww + gw);
      uint32_t p0, p1, p2, p3;
      {
        float a0 = ok ? src[0*HW] : 0.f;
        float a1 = ok ? src[1*HW] : 0.f;
        float a2 = ok ? src[2*HW] : 0.f;
        float a3 = ok ? src[3*HW] : 0.f;
        float a4 = ok ? src[4*HW] : 0.f;
        float a5 = ok ? src[5*HW] : 0.f;
        float a6 = ok ? src[6*HW] : 0.f;
        float a7 = ok ? src[7*HW] : 0.f;
        p0 = bf16rne(a0) | (bf16rne(a1) << 16);
        p1 = bf16rne(a2) | (bf16rne(a3) << 16);
        p2 = bf16rne(a4) | (bf16rne(a5) << 16);
        p3 = bf16rne(a6) | (bf16rne(a7) << 16);
      }
      *(uintx4*)&ldsX2[(rw*24 + w24)*40 + cg*8] = (uintx4){p0, p1, p2, p3};
    }

    {
      int T  = tid;
      int wl = T & 15;
      int t2 = T >> 4;
      int rl = t2 & 7;
      int cg = t2 >> 3;
      const float* src = x1 + ((size_t)(b*Cc + c0 + cg*8) * HW
                               + (h0 + rl)*Ww + (w0 + wl));
      uint32_t p0, p1, p2, p3;
      float a0 = src[0*HW], a1 = src[1*HW], a2 = src[2*HW], a3 = src[3*HW];
      float a4 = src[4*HW], a5 = src[5*HW], a6 = src[6*HW], a7 = src[7*HW];
      p0 = bf16rne(a0) | (bf16rne(a1) << 16);
      p1 = bf16rne(a2) | (bf16rne(a3) << 16);
      p2 = bf16rne(a4) | (bf16rne(a5) << 16);
      p3 = bf16rne(a6) | (bf16rne(a7) << 16);
      *(uintx4*)&ldsX1[(rl*16 + wl)*40 + cg*8] = (uintx4){p0, p1, p2, p3};
    }

    __syncthreads();

    short8 bfrag = *(const short8*)&ldsX1[((2*vy + s)*16 + 8*vx + pw)*40 + quad*8];
#pragma unroll
    for (int t = 0; t < 10; ++t) {
      short8 afrag = *(const short8*)&ldsX2[((2*vy + t)*24 + 8*vx + n)*40 + quad*8];
      acc[t] = __builtin_amdgcn_mfma_f32_16x16x32_bf16(afrag, bfrag, acc[t], 0, 0, 0);
    }
  }

  const float scale = 1.0f / 128.0f;
  const int ph  = h0 + 2*vy + s;
  const int pwg = w0 + 8*vx + pw;
#pragma unroll
  for (int t = 0; t < 10; ++t) {
    int di = t - 4 - s;
    if ((unsigned)(di + 4) > 8u) continue;
#pragma unroll
    for (int r = 0; r < 4; ++r) {
      int dj = quad*4 + r - 4 - pw;
      if ((unsigned)(dj + 4) > 8u) continue;
      int kk = (di + 4) * 9 + (dj + 4);
      out[((size_t)b*Kk + kk) * HW + ph*Ww + pwg] = acc[t][r] * scale;
    }
  }
}

extern "C" void kernel_launch(void* const* d_in, const int* in_sizes, int n_in,
                              void* d_out, int out_size, void* d_ws, size_t ws_size,
                              hipStream_t stream) {
  const float* x1 = (const float*)d_in[0];
  const float* x2 = (const float*)d_in[1];
  float* out = (float*)d_out;

  const size_t elems = (size_t)Bb * HW * Cc;              // 15,728,640
  const size_t need  = 2 * elems * sizeof(ushort);        // 62,914,560 B

  if (d_ws != nullptr && ws_size >= need) {
    ushort* x1t = (ushort*)d_ws;
    ushort* x2t = x1t + elems;
    transpose_kernel<<<dim3(HW / (TPX * 4), Bb, 2), dim3(256, 1, 1), 0, stream>>>(
        x1, x2, x1t, x2t);
    corr_t3_kernel<<<dim3(1920, 1, 1), dim3(256, 1, 1), 0, stream>>>(x1t, x2t, out);
  } else {
    corr_kernel<<<dim3(960, 1, 1), dim3(512, 1, 1), 0, stream>>>(x1, x2, out);
  }
}

// Round 6
// 200.913 us; speedup vs baseline: 1.0302x; 1.0250x over previous
//
#include <hip/hip_runtime.h>
#include <stdint.h>
#include <stddef.h>

#define Bb 8
#define Cc 128
#define Hh 96
#define Ww 160
#define HW (Hh*Ww)         // 15360
#define Kk 81

typedef __attribute__((ext_vector_type(8))) short short8;
typedef __attribute__((ext_vector_type(4))) float floatx4;
typedef __attribute__((ext_vector_type(4))) unsigned int uintx4;

__device__ __forceinline__ uint32_t bf16rne(float f) {
  uint32_t u = __float_as_uint(f);
  return (u + 0x7FFFu + ((u >> 16) & 1u)) >> 16;
}

#define SBAR() __builtin_amdgcn_sched_barrier(0)

// ---------------------------------------------------------------------------
// R12: transpose is at a THROUGHPUT wall, not latency (R9/R10/R11: 58.5us
// invariant across occupancy 31%<->60% and three schedules; 3.26 TB/s
// combined = 52% of copy ceiling, VALU 5%, conflicts nil). The invariant is
// the access shape: 8 x 128B read segments per wave-load at stride 0x3C000
// (low 13 bits zero -> degenerate HBM-channel alignment). Fix the SHAPE:
// 128px x 128ch tile -> each wave-load reads 2 x 512B segments (4x fewer,
// 4x larger). 16 passes, all 16 float4 loads issued up front (named regs).
// LDS f32 [128][129] (scatter 4-way ~1.6x, phase-2 reads 2-way free),
// 66KB -> 2 blocks/CU (occupancy proven irrelevant here). Identical bytes
// + rounding -> bit-identical. corr_t3 (~34us) + fallback unchanged.
// ---------------------------------------------------------------------------

// ---- transpose+convert: (B,C,H,W) f32 -> (B,HW,C) bf16 --------------------
#define TPX2 128
#define LSTR 129
__global__ __launch_bounds__(256, 2)
void transpose_kernel(const float* __restrict__ x1, const float* __restrict__ x2,
                      ushort* __restrict__ x1t, ushort* __restrict__ x2t) {
  __shared__ float lds[TPX2 * LSTR];    // 66048 B
  const int t   = threadIdx.x;
  const int b   = blockIdx.y;
  const int px0 = blockIdx.x * TPX2;
  const float* src = blockIdx.z ? x2 : x1;
  ushort*      dst = blockIdx.z ? x2t : x1t;

  // ---- phase 1: 16 passes x 8 channels; c = i*8 + cb8 ----
  const int p4  = t & 31;      // which float4 (4 px) within the 128-px row
  const int cb8 = t >> 5;      // 0..7
  const float* sb = src + (size_t)b * Cc * HW + (size_t)cb8 * HW + px0 + p4 * 4;

  // issue ALL 16 loads (each wave-load = 2 channels x 512B contiguous)
  floatx4 v0  = *(const floatx4*)(sb + (size_t)( 0 * 8) * HW);
  floatx4 v1  = *(const floatx4*)(sb + (size_t)( 1 * 8) * HW);
  floatx4 v2  = *(const floatx4*)(sb + (size_t)( 2 * 8) * HW);
  floatx4 v3  = *(const floatx4*)(sb + (size_t)( 3 * 8) * HW);
  floatx4 v4  = *(const floatx4*)(sb + (size_t)( 4 * 8) * HW);
  floatx4 v5  = *(const floatx4*)(sb + (size_t)( 5 * 8) * HW);
  floatx4 v6  = *(const floatx4*)(sb + (size_t)( 6 * 8) * HW);
  floatx4 v7  = *(const floatx4*)(sb + (size_t)( 7 * 8) * HW);
  floatx4 v8  = *(const floatx4*)(sb + (size_t)( 8 * 8) * HW);
  floatx4 v9  = *(const floatx4*)(sb + (size_t)( 9 * 8) * HW);
  floatx4 v10 = *(const floatx4*)(sb + (size_t)(10 * 8) * HW);
  floatx4 v11 = *(const floatx4*)(sb + (size_t)(11 * 8) * HW);
  floatx4 v12 = *(const floatx4*)(sb + (size_t)(12 * 8) * HW);
  floatx4 v13 = *(const floatx4*)(sb + (size_t)(13 * 8) * HW);
  floatx4 v14 = *(const floatx4*)(sb + (size_t)(14 * 8) * HW);
  floatx4 v15 = *(const floatx4*)(sb + (size_t)(15 * 8) * HW);
  SBAR();

  // scatter in issue order (compiler emits counted vmcnt waits)
#define TSC(vv, ii)                                                            \
  {                                                                            \
    const int c = (ii) * 8 + cb8;                                              \
    _Pragma("unroll") for (int jj = 0; jj < 4; ++jj)                           \
        lds[(p4 * 4 + jj) * LSTR + c] = vv[jj];                                \
  }
  TSC(v0, 0)  TSC(v1, 1)  TSC(v2, 2)  TSC(v3, 3)
  TSC(v4, 4)  TSC(v5, 5)  TSC(v6, 6)  TSC(v7, 7)
  TSC(v8, 8)  TSC(v9, 9)  TSC(v10, 10) TSC(v11, 11)
  TSC(v12, 12) TSC(v13, 13) TSC(v14, 14) TSC(v15, 15)
#undef TSC

  __syncthreads();

  // ---- phase 2: 4 iterations; px = it*32 + (t>>3), chunks k0 and k0+8 ----
  const int pxl = t >> 3;      // 0..31
  const int k0  = t & 7;
#pragma unroll
  for (int it = 0; it < 4; ++it) {
    const int px = it * 32 + pxl;
    const float* rowa = &lds[px * LSTR + k0 * 8];
    const float* rowb = &lds[px * LSTR + (k0 + 8) * 8];
    float f0 = rowa[0], f1 = rowa[1], f2 = rowa[2], f3 = rowa[3];
    float f4 = rowa[4], f5 = rowa[5], f6 = rowa[6], f7 = rowa[7];
    float g0 = rowb[0], g1 = rowb[1], g2 = rowb[2], g3 = rowb[3];
    float g4 = rowb[4], g5 = rowb[5], g6 = rowb[6], g7 = rowb[7];
    uintx4 qa = (uintx4){bf16rne(f0) | (bf16rne(f1) << 16),
                         bf16rne(f2) | (bf16rne(f3) << 16),
                         bf16rne(f4) | (bf16rne(f5) << 16),
                         bf16rne(f6) | (bf16rne(f7) << 16)};
    uintx4 qb = (uintx4){bf16rne(g0) | (bf16rne(g1) << 16),
                         bf16rne(g2) | (bf16rne(g3) << 16),
                         bf16rne(g4) | (bf16rne(g5) << 16),
                         bf16rne(g6) | (bf16rne(g7) << 16)};
    ushort* dbase = &dst[((size_t)b * HW + px0 + px) * Cc];
    *(uintx4*)&dbase[k0 * 8]       = qa;
    *(uintx4*)&dbase[(k0 + 8) * 8] = qb;
  }
}

// ---- correlation: pinned register pipeline + coalesced epilogue -----------
__device__ __forceinline__ int clampi(int v, int lo, int hi) {
  return v < lo ? lo : (v > hi ? hi : v);
}

#define LOADRAW(dst, tt, ckc)                                                  \
  dst = *(const short8*)&base2c[rowoff##tt + (ckc) * 32];

#define ZSEL(v, tt)                                                            \
  v = (okw && (unsigned)(gh2b + (tt)) < (unsigned)Hh) ? v                      \
      : (short8){0, 0, 0, 0, 0, 0, 0, 0};

__global__ __launch_bounds__(256, 3)
void corr_t3_kernel(const ushort* __restrict__ x1t, const ushort* __restrict__ x2t,
                    float* __restrict__ out) {
  __shared__ float ldsOut[Kk * 66];   // 21384 B, stride-66 pad (bank spread)

  const int tid  = threadIdx.x;
  const int flat = blockIdx.x;
  const int b  = flat & 7;
  const int j  = flat >> 3;        // 0..239
  const int by = j / 10;           // 0..23
  const int bx = j - by * 10;      // 0..9
  const int w0 = bx * 16;
  const int h0 = by * 4;

  const int lane = tid & 63;
  const int wv   = tid >> 6;       // 0..3
  const int vy = wv & 1, vx = wv >> 1;
  const int n = lane & 15, quad = lane >> 4;
  const int s = n >> 3, pw = n & 7;

  floatx4 acc[10];
#pragma unroll
  for (int t = 0; t < 10; ++t) acc[t] = (floatx4){0.f, 0.f, 0.f, 0.f};

  const int gw2  = w0 - 4 + 8 * vx + n;
  const bool okw = (unsigned)gw2 < (unsigned)Ww;
  const int gw2c = clampi(gw2, 0, Ww - 1);
  const int gh2b = h0 - 4 + 2 * vy;

  const ushort* base2c = x2t + ((long)b * HW + gw2c) * Cc + quad * 8;
  const ushort* base1  = x1t + ((long)b * HW + (long)(h0 + 2 * vy + s) * Ww
                                + (w0 + 8 * vx + pw)) * Cc + quad * 8;

  const long rowoff0 = (long)clampi(gh2b + 0, 0, Hh - 1) * (Ww * Cc);
  const long rowoff1 = (long)clampi(gh2b + 1, 0, Hh - 1) * (Ww * Cc);
  const long rowoff2 = (long)clampi(gh2b + 2, 0, Hh - 1) * (Ww * Cc);
  const long rowoff3 = (long)clampi(gh2b + 3, 0, Hh - 1) * (Ww * Cc);
  const long rowoff4 = (long)clampi(gh2b + 4, 0, Hh - 1) * (Ww * Cc);
  const long rowoff5 = (long)clampi(gh2b + 5, 0, Hh - 1) * (Ww * Cc);
  const long rowoff6 = (long)clampi(gh2b + 6, 0, Hh - 1) * (Ww * Cc);
  const long rowoff7 = (long)clampi(gh2b + 7, 0, Hh - 1) * (Ww * Cc);
  const long rowoff8 = (long)clampi(gh2b + 8, 0, Hh - 1) * (Ww * Cc);
  const long rowoff9 = (long)clampi(gh2b + 9, 0, Hh - 1) * (Ww * Cc);

  const short8 bf0 = *(const short8*)&base1[0 * 32];
  const short8 bf1 = *(const short8*)&base1[1 * 32];
  const short8 bf2 = *(const short8*)&base1[2 * 32];
  const short8 bf3 = *(const short8*)&base1[3 * 32];

  short8 aA0, aA1, aA2, aA3, aA4, aA5, aA6, aA7, aA8, aA9;
  short8 aB0, aB1, aB2, aB3, aB4, aB5, aB6, aB7, aB8, aB9;

  LOADRAW(aA0, 0, 0); LOADRAW(aA1, 1, 0); LOADRAW(aA2, 2, 0); LOADRAW(aA3, 3, 0);
  LOADRAW(aA4, 4, 0); LOADRAW(aA5, 5, 0); LOADRAW(aA6, 6, 0); LOADRAW(aA7, 7, 0);
  LOADRAW(aA8, 8, 0); LOADRAW(aA9, 9, 0);
  SBAR();
  LOADRAW(aB0, 0, 1); LOADRAW(aB1, 1, 1); LOADRAW(aB2, 2, 1); LOADRAW(aB3, 3, 1);
  LOADRAW(aB4, 4, 1); LOADRAW(aB5, 5, 1); LOADRAW(aB6, 6, 1); LOADRAW(aB7, 7, 1);
  LOADRAW(aB8, 8, 1); LOADRAW(aB9, 9, 1);
  SBAR();
  ZSEL(aA0, 0); ZSEL(aA1, 1); ZSEL(aA2, 2); ZSEL(aA3, 3); ZSEL(aA4, 4);
  ZSEL(aA5, 5); ZSEL(aA6, 6); ZSEL(aA7, 7); ZSEL(aA8, 8); ZSEL(aA9, 9);
  acc[0] = __builtin_amdgcn_mfma_f32_16x16x32_bf16(aA0, bf0, acc[0], 0, 0, 0);
  acc[1] = __builtin_amdgcn_mfma_f32_16x16x32_bf16(aA1, bf0, acc[1], 0, 0, 0);
  acc[2] = __builtin_amdgcn_mfma_f32_16x16x32_bf16(aA2, bf0, acc[2], 0, 0, 0);
  acc[3] = __builtin_amdgcn_mfma_f32_16x16x32_bf16(aA3, bf0, acc[3], 0, 0, 0);
  acc[4] = __builtin_amdgcn_mfma_f32_16x16x32_bf16(aA4, bf0, acc[4], 0, 0, 0);
  acc[5] = __builtin_amdgcn_mfma_f32_16x16x32_bf16(aA5, bf0, acc[5], 0, 0, 0);
  acc[6] = __builtin_amdgcn_mfma_f32_16x16x32_bf16(aA6, bf0, acc[6], 0, 0, 0);
  acc[7] = __builtin_amdgcn_mfma_f32_16x16x32_bf16(aA7, bf0, acc[7], 0, 0, 0);
  acc[8] = __builtin_amdgcn_mfma_f32_16x16x32_bf16(aA8, bf0, acc[8], 0, 0, 0);
  acc[9] = __builtin_amdgcn_mfma_f32_16x16x32_bf16(aA9, bf0, acc[9], 0, 0, 0);
  SBAR();
  LOADRAW(aA0, 0, 2); LOADRAW(aA1, 1, 2); LOADRAW(aA2, 2, 2); LOADRAW(aA3, 3, 2);
  LOADRAW(aA4, 4, 2); LOADRAW(aA5, 5, 2); LOADRAW(aA6, 6, 2); LOADRAW(aA7, 7, 2);
  LOADRAW(aA8, 8, 2); LOADRAW(aA9, 9, 2);
  SBAR();
  ZSEL(aB0, 0); ZSEL(aB1, 1); ZSEL(aB2, 2); ZSEL(aB3, 3); ZSEL(aB4, 4);
  ZSEL(aB5, 5); ZSEL(aB6, 6); ZSEL(aB7, 7); ZSEL(aB8, 8); ZSEL(aB9, 9);
  acc[0] = __builtin_amdgcn_mfma_f32_16x16x32_bf16(aB0, bf1, acc[0], 0, 0, 0);
  acc[1] = __builtin_amdgcn_mfma_f32_16x16x32_bf16(aB1, bf1, acc[1], 0, 0, 0);
  acc[2] = __builtin_amdgcn_mfma_f32_16x16x32_bf16(aB2, bf1, acc[2], 0, 0, 0);
  acc[3] = __builtin_amdgcn_mfma_f32_16x16x32_bf16(aB3, bf1, acc[3], 0, 0, 0);
  acc[4] = __builtin_amdgcn_mfma_f32_16x16x32_bf16(aB4, bf1, acc[4], 0, 0, 0);
  acc[5] = __builtin_amdgcn_mfma_f32_16x16x32_bf16(aB5, bf1, acc[5], 0, 0, 0);
  acc[6] = __builtin_amdgcn_mfma_f32_16x16x32_bf16(aB6, bf1, acc[6], 0, 0, 0);
  acc[7] = __builtin_amdgcn_mfma_f32_16x16x32_bf16(aB7, bf1, acc[7], 0, 0, 0);
  acc[8] = __builtin_amdgcn_mfma_f32_16x16x32_bf16(aB8, bf1, acc[8], 0, 0, 0);
  acc[9] = __builtin_amdgcn_mfma_f32_16x16x32_bf16(aB9, bf1, acc[9], 0, 0, 0);
  SBAR();
  LOADRAW(aB0, 0, 3); LOADRAW(aB1, 1, 3); LOADRAW(aB2, 2, 3); LOADRAW(aB3, 3, 3);
  LOADRAW(aB4, 4, 3); LOADRAW(aB5, 5, 3); LOADRAW(aB6, 6, 3); LOADRAW(aB7, 7, 3);
  LOADRAW(aB8, 8, 3); LOADRAW(aB9, 9, 3);
  SBAR();
  ZSEL(aA0, 0); ZSEL(aA1, 1); ZSEL(aA2, 2); ZSEL(aA3, 3); ZSEL(aA4, 4);
  ZSEL(aA5, 5); ZSEL(aA6, 6); ZSEL(aA7, 7); ZSEL(aA8, 8); ZSEL(aA9, 9);
  acc[0] = __builtin_amdgcn_mfma_f32_16x16x32_bf16(aA0, bf2, acc[0], 0, 0, 0);
  acc[1] = __builtin_amdgcn_mfma_f32_16x16x32_bf16(aA1, bf2, acc[1], 0, 0, 0);
  acc[2] = __builtin_amdgcn_mfma_f32_16x16x32_bf16(aA2, bf2, acc[2], 0, 0, 0);
  acc[3] = __builtin_amdgcn_mfma_f32_16x16x32_bf16(aA3, bf2, acc[3], 0, 0, 0);
  acc[4] = __builtin_amdgcn_mfma_f32_16x16x32_bf16(aA4, bf2, acc[4], 0, 0, 0);
  acc[5] = __builtin_amdgcn_mfma_f32_16x16x32_bf16(aA5, bf2, acc[5], 0, 0, 0);
  acc[6] = __builtin_amdgcn_mfma_f32_16x16x32_bf16(aA6, bf2, acc[6], 0, 0, 0);
  acc[7] = __builtin_amdgcn_mfma_f32_16x16x32_bf16(aA7, bf2, acc[7], 0, 0, 0);
  acc[8] = __builtin_amdgcn_mfma_f32_16x16x32_bf16(aA8, bf2, acc[8], 0, 0, 0);
  acc[9] = __builtin_amdgcn_mfma_f32_16x16x32_bf16(aA9, bf2, acc[9], 0, 0, 0);
  SBAR();
  ZSEL(aB0, 0); ZSEL(aB1, 1); ZSEL(aB2, 2); ZSEL(aB3, 3); ZSEL(aB4, 4);
  ZSEL(aB5, 5); ZSEL(aB6, 6); ZSEL(aB7, 7); ZSEL(aB8, 8); ZSEL(aB9, 9);
  acc[0] = __builtin_amdgcn_mfma_f32_16x16x32_bf16(aB0, bf3, acc[0], 0, 0, 0);
  acc[1] = __builtin_amdgcn_mfma_f32_16x16x32_bf16(aB1, bf3, acc[1], 0, 0, 0);
  acc[2] = __builtin_amdgcn_mfma_f32_16x16x32_bf16(aB2, bf3, acc[2], 0, 0, 0);
  acc[3] = __builtin_amdgcn_mfma_f32_16x16x32_bf16(aB3, bf3, acc[3], 0, 0, 0);
  acc[4] = __builtin_amdgcn_mfma_f32_16x16x32_bf16(aB4, bf3, acc[4], 0, 0, 0);
  acc[5] = __builtin_amdgcn_mfma_f32_16x16x32_bf16(aB5, bf3, acc[5], 0, 0, 0);
  acc[6] = __builtin_amdgcn_mfma_f32_16x16x32_bf16(aB6, bf3, acc[6], 0, 0, 0);
  acc[7] = __builtin_amdgcn_mfma_f32_16x16x32_bf16(aB7, bf3, acc[7], 0, 0, 0);
  acc[8] = __builtin_amdgcn_mfma_f32_16x16x32_bf16(aB8, bf3, acc[8], 0, 0, 0);
  acc[9] = __builtin_amdgcn_mfma_f32_16x16x32_bf16(aB9, bf3, acc[9], 0, 0, 0);

  // ---- epilogue: scatter to padded LDS, then coalesced full-line writes ----
  const float scale = 1.0f / 128.0f;
  const int prow = 2 * vy + s;           // 0..3 within tile
  const int pcol = 8 * vx + pw;          // 0..15 within tile
#pragma unroll
  for (int t = 0; t < 10; ++t) {
    int di = t - 4 - s;
    if ((unsigned)(di + 4) > 8u) continue;
#pragma unroll
    for (int r = 0; r < 4; ++r) {
      int dj = quad * 4 + r - 4 - pw;
      if ((unsigned)(dj + 4) > 8u) continue;
      int kk = (di + 4) * 9 + (dj + 4);
      ldsOut[kk * 66 + prow * 16 + pcol] = acc[t][r] * scale;
    }
  }
  __syncthreads();

  for (int idx = tid; idx < Kk * 64; idx += 256) {
    int kk  = idx >> 6;
    int rem = idx & 63;                  // hh*16 + ww
    int hh  = rem >> 4;
    int ww  = rem & 15;
    out[((size_t)b * Kk + kk) * HW + (size_t)(h0 + hh) * Ww + (w0 + ww)] =
        ldsOut[kk * 66 + rem];
  }
}

// ---------------------------------------------------------------------------
// R6 kernel kept verbatim as fallback when workspace is too small.
// ---------------------------------------------------------------------------
__global__ __launch_bounds__(512, 4)
void corr_kernel(const float* __restrict__ x1, const float* __restrict__ x2,
                 float* __restrict__ out) {
  __shared__ __align__(16) ushort ldsX2[16*24*40];
  __shared__ __align__(16) ushort ldsX1[8*16*40];

  const int tid = threadIdx.x;
  const int flat = blockIdx.x;
  const int b  = flat & 7;
  const int j  = flat >> 3;
  const int by = j / 10;
  const int bx = j - by * 10;
  const int w0 = bx * 16;
  const int h0 = by * 8;

  const int lane = tid & 63;
  const int wv   = tid >> 6;
  const int vy = wv & 3, vx = wv >> 2;
  const int n = lane & 15, quad = lane >> 4;
  const int s = n >> 3, pw = n & 7;

  floatx4 acc[10];
#pragma unroll
  for (int t = 0; t < 10; ++t) acc[t] = (floatx4){0.f, 0.f, 0.f, 0.f};

  for (int ck = 0; ck < 4; ++ck) {
    const int c0 = ck * 32;
    if (ck) __syncthreads();

#pragma unroll
    for (int it = 0; it < 3; ++it) {
      int T   = it * 512 + tid;
      int w24 = T % 24;
      int t2  = T / 24;
      int rw  = t2 & 15;
      int cg  = t2 >> 4;
      int gh = h0 - 4 + rw;
      int gw = w0 - 4 + w24;
      bool ok = ((unsigned)gh < Hh) && ((unsigned)gw < Ww);
      const float* src = x2 + ((size_t)(b*Cc + c0 + cg*8) * HW + gh*Ww + gw);
      uint32_t p0, p1, p2, p3;
      {
        float a0 = ok ? src[0*HW] : 0.f;
        float a1 = ok ? src[1*HW] : 0.f;
        float a2 = ok ? src[2*HW] : 0.f;
        float a3 = ok ? src[3*HW] : 0.f;
        float a4 = ok ? src[4*HW] : 0.f;
        float a5 = ok ? src[5*HW] : 0.f;
        float a6 = ok ? src[6*HW] : 0.f;
        float a7 = ok ? src[7*HW] : 0.f;
        p0 = bf16rne(a0) | (bf16rne(a1) << 16);
        p1 = bf16rne(a2) | (bf16rne(a3) << 16);
        p2 = bf16rne(a4) | (bf16rne(a5) << 16);
        p3 = bf16rne(a6) | (bf16rne(a7) << 16);
      }
      *(uintx4*)&ldsX2[(rw*24 + w24)*40 + cg*8] = (uintx4){p0, p1, p2, p3};
    }

    {
      int T  = tid;
      int wl = T & 15;
      int t2 = T >> 4;
      int rl = t2 & 7;
      int cg = t2 >> 3;
      const float* src = x1 + ((size_t)(b*Cc + c0 + cg*8) * HW
                               + (h0 + rl)*Ww + (w0 + wl));
      uint32_t p0, p1, p2, p3;
      float a0 = src[0*HW], a1 = src[1*HW], a2 = src[2*HW], a3 = src[3*HW];
      float a4 = src[4*HW], a5 = src[5*HW], a6 = src[6*HW], a7 = src[7*HW];
      p0 = bf16rne(a0) | (bf16rne(a1) << 16);
      p1 = bf16rne(a2) | (bf16rne(a3) << 16);
      p2 = bf16rne(a4) | (bf16rne(a5) << 16);
      p3 = bf16rne(a6) | (bf16rne(a7) << 16);
      *(uintx4*)&ldsX1[(rl*16 + wl)*40 + cg*8] = (uintx4){p0, p1, p2, p3};
    }

    __syncthreads();

    short8 bfrag = *(const short8*)&ldsX1[((2*vy + s)*16 + 8*vx + pw)*40 + quad*8];
#pragma unroll
    for (int t = 0; t < 10; ++t) {
      short8 afrag = *(const short8*)&ldsX2[((2*vy + t)*24 + 8*vx + n)*40 + quad*8];
      acc[t] = __builtin_amdgcn_mfma_f32_16x16x32_bf16(afrag, bfrag, acc[t], 0, 0, 0);
    }
  }

  const float scale = 1.0f / 128.0f;
  const int ph  = h0 + 2*vy + s;
  const int pwg = w0 + 8*vx + pw;
#pragma unroll
  for (int t = 0; t < 10; ++t) {
    int di = t - 4 - s;
    if ((unsigned)(di + 4) > 8u) continue;
#pragma unroll
    for (int r = 0; r < 4; ++r) {
      int dj = quad*4 + r - 4 - pw;
      if ((unsigned)(dj + 4) > 8u) continue;
      int kk = (di + 4) * 9 + (dj + 4);
      out[((size_t)b*Kk + kk) * HW + ph*Ww + pwg] = acc[t][r] * scale;
    }
  }
}

extern "C" void kernel_launch(void* const* d_in, const int* in_sizes, int n_in,
                              void* d_out, int out_size, void* d_ws, size_t ws_size,
                              hipStream_t stream) {
  const float* x1 = (const float*)d_in[0];
  const float* x2 = (const float*)d_in[1];
  float* out = (float*)d_out;

  const size_t elems = (size_t)Bb * HW * Cc;              // 15,728,640
  const size_t need  = 2 * elems * sizeof(ushort);        // 62,914,560 B

  if (d_ws != nullptr && ws_size >= need) {
    ushort* x1t = (ushort*)d_ws;
    ushort* x2t = x1t + elems;
    transpose_kernel<<<dim3(HW / TPX2, Bb, 2), dim3(256, 1, 1), 0, stream>>>(
        x1, x2, x1t, x2t);
    corr_t3_kernel<<<dim3(1920, 1, 1), dim3(256, 1, 1), 0, stream>>>(x1t, x2t, out);
  } else {
    corr_kernel<<<dim3(960, 1, 1), dim3(512, 1, 1), 0, stream>>>(x1, x2, out);
  }
}

// Round 7
// 181.252 us; speedup vs baseline: 1.1419x; 1.1085x over previous
//
#include <hip/hip_runtime.h>
#include <stdint.h>
#include <stddef.h>

#define Bb 8
#define Cc 128
#define Hh 96
#define Ww 160
#define HW (Hh*Ww)         // 15360
#define Kk 81

typedef __attribute__((ext_vector_type(8))) short short8;
typedef __attribute__((ext_vector_type(4))) float floatx4;
typedef __attribute__((ext_vector_type(4))) unsigned int uintx4;

__device__ __forceinline__ uint32_t bf16rne(float f) {
  uint32_t u = __float_as_uint(f);
  return (u + 0x7FFFu + ((u >> 16) & 1u)) >> 16;
}

#define SBAR() __builtin_amdgcn_sched_barrier(0)

// ---------------------------------------------------------------------------
// R13: layout change #2. The intermediate only needs 8-channel granularity
// (corr fragments = 8 consecutive channels), so use (B, C/8, HW, 8ch) bf16
// instead of (B, HW, C). Transpose becomes an 8-deep shuffle:
//   reads  = 1024B contiguous per wave-load  (copy-kernel pattern),
//   writes = 1024B contiguous per wave-store,
//   LDS    = 16.5KB conflict-free both phases, 8 blocks/CU.
// (R12 postmortem: 54us with 16% occupancy, 3.9M conflict-cycles, 66KB LDS,
// 16 scattered streams/wave -- this removes all of those at once.)
// corr reads improve too: 4 x 256B segments per wave-load (was 16 x 64B).
// Channel->lane mapping unchanged -> bit-identical numerics.
// ---------------------------------------------------------------------------

// ---- transpose+convert: (B,C,H,W) f32 -> (B, C/8, HW, 8) bf16 -------------
#define TPX3 512
__global__ __launch_bounds__(256, 8)
void transpose_kernel(const float* __restrict__ x1, const float* __restrict__ x2,
                      ushort* __restrict__ x1t, ushort* __restrict__ x2t) {
  __shared__ float lds[8][TPX3 + 4];    // 16512 B, conflict-free both phases
  const int t   = threadIdx.x;
  const int b   = blockIdx.y;
  const int px0 = blockIdx.x * TPX3;
  const int zz  = blockIdx.z;           // 0..31 = tensor*16 + cg
  const int cg  = zz & 15;
  const float* src = (zz >> 4) ? x2 : x1;
  ushort*      dst = (zz >> 4) ? x2t : x1t;

  // ---- phase 1: 4 loads/thread; each wave-load = 1024B contiguous ----
  const int hi  = t >> 7;               // 0..1 (uniform per wave)
  const int pos = t & 127;              // float4 index within 512-px row
  const float* sb = src + ((size_t)(b * Cc + cg * 8 + hi)) * HW + px0 + pos * 4;
  floatx4 v0 = *(const floatx4*)(sb + (size_t)0 * HW);
  floatx4 v1 = *(const floatx4*)(sb + (size_t)2 * HW);
  floatx4 v2 = *(const floatx4*)(sb + (size_t)4 * HW);
  floatx4 v3 = *(const floatx4*)(sb + (size_t)6 * HW);
  SBAR();
  // b128 LDS writes, lane-linear within each row -> conflict-free
  *(floatx4*)&lds[0 + hi][pos * 4] = v0;
  *(floatx4*)&lds[2 + hi][pos * 4] = v1;
  *(floatx4*)&lds[4 + hi][pos * 4] = v2;
  *(floatx4*)&lds[6 + hi][pos * 4] = v3;

  __syncthreads();

  // ---- phase 2: 2 px/thread; pack 8ch bf16; 1024B contiguous wave-stores --
  ushort* dbase = dst + (((size_t)b * 16 + cg) * HW + px0) * 8;
#pragma unroll
  for (int j = 0; j < 2; ++j) {
    const int px = j * 256 + t;
    float c0 = lds[0][px], c1 = lds[1][px], c2 = lds[2][px], c3 = lds[3][px];
    float c4 = lds[4][px], c5 = lds[5][px], c6 = lds[6][px], c7 = lds[7][px];
    uintx4 q = (uintx4){bf16rne(c0) | (bf16rne(c1) << 16),
                        bf16rne(c2) | (bf16rne(c3) << 16),
                        bf16rne(c4) | (bf16rne(c5) << 16),
                        bf16rne(c6) | (bf16rne(c7) << 16)};
    *(uintx4*)&dbase[(size_t)px * 8] = q;
  }
}

// ---- correlation on (B, C/8, HW, 8) bf16 ----------------------------------
__device__ __forceinline__ int clampi(int v, int lo, int hi) {
  return v < lo ? lo : (v > hi ? hi : v);
}

// plane step per ck: cg advances by 4 -> 4*HW*8 ushorts
#define CKSTEP ((long)4 * HW * 8)

#define LOADRAW(dst, tt, ckc)                                                  \
  dst = *(const short8*)&base2c[rowoff##tt + (ckc) * CKSTEP];

#define ZSEL(v, tt)                                                            \
  v = (okw && (unsigned)(gh2b + (tt)) < (unsigned)Hh) ? v                      \
      : (short8){0, 0, 0, 0, 0, 0, 0, 0};

__global__ __launch_bounds__(256, 3)
void corr_t3_kernel(const ushort* __restrict__ x1t, const ushort* __restrict__ x2t,
                    float* __restrict__ out) {
  __shared__ float ldsOut[Kk * 66];   // 21384 B, stride-66 pad (bank spread)

  const int tid  = threadIdx.x;
  const int flat = blockIdx.x;
  const int b  = flat & 7;
  const int j  = flat >> 3;        // 0..239
  const int by = j / 10;           // 0..23
  const int bx = j - by * 10;      // 0..9
  const int w0 = bx * 16;
  const int h0 = by * 4;

  const int lane = tid & 63;
  const int wv   = tid >> 6;       // 0..3
  const int vy = wv & 1, vx = wv >> 1;
  const int n = lane & 15, quad = lane >> 4;
  const int s = n >> 3, pw = n & 7;

  floatx4 acc[10];
#pragma unroll
  for (int t = 0; t < 10; ++t) acc[t] = (floatx4){0.f, 0.f, 0.f, 0.f};

  const int gw2  = w0 - 4 + 8 * vx + n;
  const bool okw = (unsigned)gw2 < (unsigned)Ww;
  const int gw2c = clampi(gw2, 0, Ww - 1);
  const int gh2b = h0 - 4 + 2 * vy;

  // plane = b*16 + (ck*4 + quad); px = gh*Ww + gw
  const ushort* base2c = x2t + (((long)b * 16 + quad) * HW + gw2c) * 8;
  const ushort* base1  = x1t + (((long)b * 16 + quad) * HW
                                + (long)(h0 + 2 * vy + s) * Ww
                                + (w0 + 8 * vx + pw)) * 8;

  const long rowoff0 = (long)clampi(gh2b + 0, 0, Hh - 1) * (Ww * 8);
  const long rowoff1 = (long)clampi(gh2b + 1, 0, Hh - 1) * (Ww * 8);
  const long rowoff2 = (long)clampi(gh2b + 2, 0, Hh - 1) * (Ww * 8);
  const long rowoff3 = (long)clampi(gh2b + 3, 0, Hh - 1) * (Ww * 8);
  const long rowoff4 = (long)clampi(gh2b + 4, 0, Hh - 1) * (Ww * 8);
  const long rowoff5 = (long)clampi(gh2b + 5, 0, Hh - 1) * (Ww * 8);
  const long rowoff6 = (long)clampi(gh2b + 6, 0, Hh - 1) * (Ww * 8);
  const long rowoff7 = (long)clampi(gh2b + 7, 0, Hh - 1) * (Ww * 8);
  const long rowoff8 = (long)clampi(gh2b + 8, 0, Hh - 1) * (Ww * 8);
  const long rowoff9 = (long)clampi(gh2b + 9, 0, Hh - 1) * (Ww * 8);

  const short8 bf0 = *(const short8*)&base1[0 * CKSTEP];
  const short8 bf1 = *(const short8*)&base1[1 * CKSTEP];
  const short8 bf2 = *(const short8*)&base1[2 * CKSTEP];
  const short8 bf3 = *(const short8*)&base1[3 * CKSTEP];

  short8 aA0, aA1, aA2, aA3, aA4, aA5, aA6, aA7, aA8, aA9;
  short8 aB0, aB1, aB2, aB3, aB4, aB5, aB6, aB7, aB8, aB9;

  LOADRAW(aA0, 0, 0); LOADRAW(aA1, 1, 0); LOADRAW(aA2, 2, 0); LOADRAW(aA3, 3, 0);
  LOADRAW(aA4, 4, 0); LOADRAW(aA5, 5, 0); LOADRAW(aA6, 6, 0); LOADRAW(aA7, 7, 0);
  LOADRAW(aA8, 8, 0); LOADRAW(aA9, 9, 0);
  SBAR();
  LOADRAW(aB0, 0, 1); LOADRAW(aB1, 1, 1); LOADRAW(aB2, 2, 1); LOADRAW(aB3, 3, 1);
  LOADRAW(aB4, 4, 1); LOADRAW(aB5, 5, 1); LOADRAW(aB6, 6, 1); LOADRAW(aB7, 7, 1);
  LOADRAW(aB8, 8, 1); LOADRAW(aB9, 9, 1);
  SBAR();
  ZSEL(aA0, 0); ZSEL(aA1, 1); ZSEL(aA2, 2); ZSEL(aA3, 3); ZSEL(aA4, 4);
  ZSEL(aA5, 5); ZSEL(aA6, 6); ZSEL(aA7, 7); ZSEL(aA8, 8); ZSEL(aA9, 9);
  acc[0] = __builtin_amdgcn_mfma_f32_16x16x32_bf16(aA0, bf0, acc[0], 0, 0, 0);
  acc[1] = __builtin_amdgcn_mfma_f32_16x16x32_bf16(aA1, bf0, acc[1], 0, 0, 0);
  acc[2] = __builtin_amdgcn_mfma_f32_16x16x32_bf16(aA2, bf0, acc[2], 0, 0, 0);
  acc[3] = __builtin_amdgcn_mfma_f32_16x16x32_bf16(aA3, bf0, acc[3], 0, 0, 0);
  acc[4] = __builtin_amdgcn_mfma_f32_16x16x32_bf16(aA4, bf0, acc[4], 0, 0, 0);
  acc[5] = __builtin_amdgcn_mfma_f32_16x16x32_bf16(aA5, bf0, acc[5], 0, 0, 0);
  acc[6] = __builtin_amdgcn_mfma_f32_16x16x32_bf16(aA6, bf0, acc[6], 0, 0, 0);
  acc[7] = __builtin_amdgcn_mfma_f32_16x16x32_bf16(aA7, bf0, acc[7], 0, 0, 0);
  acc[8] = __builtin_amdgcn_mfma_f32_16x16x32_bf16(aA8, bf0, acc[8], 0, 0, 0);
  acc[9] = __builtin_amdgcn_mfma_f32_16x16x32_bf16(aA9, bf0, acc[9], 0, 0, 0);
  SBAR();
  LOADRAW(aA0, 0, 2); LOADRAW(aA1, 1, 2); LOADRAW(aA2, 2, 2); LOADRAW(aA3, 3, 2);
  LOADRAW(aA4, 4, 2); LOADRAW(aA5, 5, 2); LOADRAW(aA6, 6, 2); LOADRAW(aA7, 7, 2);
  LOADRAW(aA8, 8, 2); LOADRAW(aA9, 9, 2);
  SBAR();
  ZSEL(aB0, 0); ZSEL(aB1, 1); ZSEL(aB2, 2); ZSEL(aB3, 3); ZSEL(aB4, 4);
  ZSEL(aB5, 5); ZSEL(aB6, 6); ZSEL(aB7, 7); ZSEL(aB8, 8); ZSEL(aB9, 9);
  acc[0] = __builtin_amdgcn_mfma_f32_16x16x32_bf16(aB0, bf1, acc[0], 0, 0, 0);
  acc[1] = __builtin_amdgcn_mfma_f32_16x16x32_bf16(aB1, bf1, acc[1], 0, 0, 0);
  acc[2] = __builtin_amdgcn_mfma_f32_16x16x32_bf16(aB2, bf1, acc[2], 0, 0, 0);
  acc[3] = __builtin_amdgcn_mfma_f32_16x16x32_bf16(aB3, bf1, acc[3], 0, 0, 0);
  acc[4] = __builtin_amdgcn_mfma_f32_16x16x32_bf16(aB4, bf1, acc[4], 0, 0, 0);
  acc[5] = __builtin_amdgcn_mfma_f32_16x16x32_bf16(aB5, bf1, acc[5], 0, 0, 0);
  acc[6] = __builtin_amdgcn_mfma_f32_16x16x32_bf16(aB6, bf1, acc[6], 0, 0, 0);
  acc[7] = __builtin_amdgcn_mfma_f32_16x16x32_bf16(aB7, bf1, acc[7], 0, 0, 0);
  acc[8] = __builtin_amdgcn_mfma_f32_16x16x32_bf16(aB8, bf1, acc[8], 0, 0, 0);
  acc[9] = __builtin_amdgcn_mfma_f32_16x16x32_bf16(aB9, bf1, acc[9], 0, 0, 0);
  SBAR();
  LOADRAW(aB0, 0, 3); LOADRAW(aB1, 1, 3); LOADRAW(aB2, 2, 3); LOADRAW(aB3, 3, 3);
  LOADRAW(aB4, 4, 3); LOADRAW(aB5, 5, 3); LOADRAW(aB6, 6, 3); LOADRAW(aB7, 7, 3);
  LOADRAW(aB8, 8, 3); LOADRAW(aB9, 9, 3);
  SBAR();
  ZSEL(aA0, 0); ZSEL(aA1, 1); ZSEL(aA2, 2); ZSEL(aA3, 3); ZSEL(aA4, 4);
  ZSEL(aA5, 5); ZSEL(aA6, 6); ZSEL(aA7, 7); ZSEL(aA8, 8); ZSEL(aA9, 9);
  acc[0] = __builtin_amdgcn_mfma_f32_16x16x32_bf16(aA0, bf2, acc[0], 0, 0, 0);
  acc[1] = __builtin_amdgcn_mfma_f32_16x16x32_bf16(aA1, bf2, acc[1], 0, 0, 0);
  acc[2] = __builtin_amdgcn_mfma_f32_16x16x32_bf16(aA2, bf2, acc[2], 0, 0, 0);
  acc[3] = __builtin_amdgcn_mfma_f32_16x16x32_bf16(aA3, bf2, acc[3], 0, 0, 0);
  acc[4] = __builtin_amdgcn_mfma_f32_16x16x32_bf16(aA4, bf2, acc[4], 0, 0, 0);
  acc[5] = __builtin_amdgcn_mfma_f32_16x16x32_bf16(aA5, bf2, acc[5], 0, 0, 0);
  acc[6] = __builtin_amdgcn_mfma_f32_16x16x32_bf16(aA6, bf2, acc[6], 0, 0, 0);
  acc[7] = __builtin_amdgcn_mfma_f32_16x16x32_bf16(aA7, bf2, acc[7], 0, 0, 0);
  acc[8] = __builtin_amdgcn_mfma_f32_16x16x32_bf16(aA8, bf2, acc[8], 0, 0, 0);
  acc[9] = __builtin_amdgcn_mfma_f32_16x16x32_bf16(aA9, bf2, acc[9], 0, 0, 0);
  SBAR();
  ZSEL(aB0, 0); ZSEL(aB1, 1); ZSEL(aB2, 2); ZSEL(aB3, 3); ZSEL(aB4, 4);
  ZSEL(aB5, 5); ZSEL(aB6, 6); ZSEL(aB7, 7); ZSEL(aB8, 8); ZSEL(aB9, 9);
  acc[0] = __builtin_amdgcn_mfma_f32_16x16x32_bf16(aB0, bf3, acc[0], 0, 0, 0);
  acc[1] = __builtin_amdgcn_mfma_f32_16x16x32_bf16(aB1, bf3, acc[1], 0, 0, 0);
  acc[2] = __builtin_amdgcn_mfma_f32_16x16x32_bf16(aB2, bf3, acc[2], 0, 0, 0);
  acc[3] = __builtin_amdgcn_mfma_f32_16x16x32_bf16(aB3, bf3, acc[3], 0, 0, 0);
  acc[4] = __builtin_amdgcn_mfma_f32_16x16x32_bf16(aB4, bf3, acc[4], 0, 0, 0);
  acc[5] = __builtin_amdgcn_mfma_f32_16x16x32_bf16(aB5, bf3, acc[5], 0, 0, 0);
  acc[6] = __builtin_amdgcn_mfma_f32_16x16x32_bf16(aB6, bf3, acc[6], 0, 0, 0);
  acc[7] = __builtin_amdgcn_mfma_f32_16x16x32_bf16(aB7, bf3, acc[7], 0, 0, 0);
  acc[8] = __builtin_amdgcn_mfma_f32_16x16x32_bf16(aB8, bf3, acc[8], 0, 0, 0);
  acc[9] = __builtin_amdgcn_mfma_f32_16x16x32_bf16(aB9, bf3, acc[9], 0, 0, 0);

  // ---- epilogue: scatter to padded LDS, then coalesced full-line writes ----
  const float scale = 1.0f / 128.0f;
  const int prow = 2 * vy + s;           // 0..3 within tile
  const int pcol = 8 * vx + pw;          // 0..15 within tile
#pragma unroll
  for (int t = 0; t < 10; ++t) {
    int di = t - 4 - s;
    if ((unsigned)(di + 4) > 8u) continue;
#pragma unroll
    for (int r = 0; r < 4; ++r) {
      int dj = quad * 4 + r - 4 - pw;
      if ((unsigned)(dj + 4) > 8u) continue;
      int kk = (di + 4) * 9 + (dj + 4);
      ldsOut[kk * 66 + prow * 16 + pcol] = acc[t][r] * scale;
    }
  }
  __syncthreads();

  for (int idx = tid; idx < Kk * 64; idx += 256) {
    int kk  = idx >> 6;
    int rem = idx & 63;                  // hh*16 + ww
    int hh  = rem >> 4;
    int ww  = rem & 15;
    out[((size_t)b * Kk + kk) * HW + (size_t)(h0 + hh) * Ww + (w0 + ww)] =
        ldsOut[kk * 66 + rem];
  }
}

// ---------------------------------------------------------------------------
// R6 kernel kept verbatim as fallback when workspace is too small.
// ---------------------------------------------------------------------------
__global__ __launch_bounds__(512, 4)
void corr_kernel(const float* __restrict__ x1, const float* __restrict__ x2,
                 float* __restrict__ out) {
  __shared__ __align__(16) ushort ldsX2[16*24*40];
  __shared__ __align__(16) ushort ldsX1[8*16*40];

  const int tid = threadIdx.x;
  const int flat = blockIdx.x;
  const int b  = flat & 7;
  const int j  = flat >> 3;
  const int by = j / 10;
  const int bx = j - by * 10;
  const int w0 = bx * 16;
  const int h0 = by * 8;

  const int lane = tid & 63;
  const int wv   = tid >> 6;
  const int vy = wv & 3, vx = wv >> 2;
  const int n = lane & 15, quad = lane >> 4;
  const int s = n >> 3, pw = n & 7;

  floatx4 acc[10];
#pragma unroll
  for (int t = 0; t < 10; ++t) acc[t] = (floatx4){0.f, 0.f, 0.f, 0.f};

  for (int ck = 0; ck < 4; ++ck) {
    const int c0 = ck * 32;
    if (ck) __syncthreads();

#pragma unroll
    for (int it = 0; it < 3; ++it) {
      int T   = it * 512 + tid;
      int w24 = T % 24;
      int t2  = T / 24;
      int rw  = t2 & 15;
      int cg  = t2 >> 4;
      int gh = h0 - 4 + rw;
      int gw = w0 - 4 + w24;
      bool ok = ((unsigned)gh < Hh) && ((unsigned)gw < Ww);
      const float* src = x2 + ((size_t)(b*Cc + c0 + cg*8) * HW + gh*Ww + gw);
      uint32_t p0, p1, p2, p3;
      {
        float a0 = ok ? src[0*HW] : 0.f;
        float a1 = ok ? src[1*HW] : 0.f;
        float a2 = ok ? src[2*HW] : 0.f;
        float a3 = ok ? src[3*HW] : 0.f;
        float a4 = ok ? src[4*HW] : 0.f;
        float a5 = ok ? src[5*HW] : 0.f;
        float a6 = ok ? src[6*HW] : 0.f;
        float a7 = ok ? src[7*HW] : 0.f;
        p0 = bf16rne(a0) | (bf16rne(a1) << 16);
        p1 = bf16rne(a2) | (bf16rne(a3) << 16);
        p2 = bf16rne(a4) | (bf16rne(a5) << 16);
        p3 = bf16rne(a6) | (bf16rne(a7) << 16);
      }
      *(uintx4*)&ldsX2[(rw*24 + w24)*40 + cg*8] = (uintx4){p0, p1, p2, p3};
    }

    {
      int T  = tid;
      int wl = T & 15;
      int t2 = T >> 4;
      int rl = t2 & 7;
      int cg = t2 >> 3;
      const float* src = x1 + ((size_t)(b*Cc + c0 + cg*8) * HW
                               + (h0 + rl)*Ww + (w0 + wl));
      uint32_t p0, p1, p2, p3;
      float a0 = src[0*HW], a1 = src[1*HW], a2 = src[2*HW], a3 = src[3*HW];
      float a4 = src[4*HW], a5 = src[5*HW], a6 = src[6*HW], a7 = src[7*HW];
      p0 = bf16rne(a0) | (bf16rne(a1) << 16);
      p1 = bf16rne(a2) | (bf16rne(a3) << 16);
      p2 = bf16rne(a4) | (bf16rne(a5) << 16);
      p3 = bf16rne(a6) | (bf16rne(a7) << 16);
      *(uintx4*)&ldsX1[(rl*16 + wl)*40 + cg*8] = (uintx4){p0, p1, p2, p3};
    }

    __syncthreads();

    short8 bfrag = *(const short8*)&ldsX1[((2*vy + s)*16 + 8*vx + pw)*40 + quad*8];
#pragma unroll
    for (int t = 0; t < 10; ++t) {
      short8 afrag = *(const short8*)&ldsX2[((2*vy + t)*24 + 8*vx + n)*40 + quad*8];
      acc[t] = __builtin_amdgcn_mfma_f32_16x16x32_bf16(afrag, bfrag, acc[t], 0, 0, 0);
    }
  }

  const float scale = 1.0f / 128.0f;
  const int ph  = h0 + 2*vy + s;
  const int pwg = w0 + 8*vx + pw;
#pragma unroll
  for (int t = 0; t < 10; ++t) {
    int di = t - 4 - s;
    if ((unsigned)(di + 4) > 8u) continue;
#pragma unroll
    for (int r = 0; r < 4; ++r) {
      int dj = quad*4 + r - 4 - pw;
      if ((unsigned)(dj + 4) > 8u) continue;
      int kk = (di + 4) * 9 + (dj + 4);
      out[((size_t)b*Kk + kk) * HW + ph*Ww + pwg] = acc[t][r] * scale;
    }
  }
}

extern "C" void kernel_launch(void* const* d_in, const int* in_sizes, int n_in,
                              void* d_out, int out_size, void* d_ws, size_t ws_size,
                              hipStream_t stream) {
  const float* x1 = (const float*)d_in[0];
  const float* x2 = (const float*)d_in[1];
  float* out = (float*)d_out;

  const size_t elems = (size_t)Bb * HW * Cc;              // 15,728,640
  const size_t need  = 2 * elems * sizeof(ushort);        // 62,914,560 B

  if (d_ws != nullptr && ws_size >= need) {
    ushort* x1t = (ushort*)d_ws;
    ushort* x2t = x1t + elems;
    transpose_kernel<<<dim3(HW / TPX3, Bb, 32), dim3(256, 1, 1), 0, stream>>>(
        x1, x2, x1t, x2t);
    corr_t3_kernel<<<dim3(1920, 1, 1), dim3(256, 1, 1), 0, stream>>>(x1t, x2t, out);
  } else {
    corr_kernel<<<dim3(960, 1, 1), dim3(512, 1, 1), 0, stream>>>(x1, x2, out);
  }
}